// Round 1
// 207.932 us; speedup vs baseline: 1.0566x; 1.0566x over previous
//
#include <hip/hip_runtime.h>
#include <cstdint>

// ---------------- ws layout (bytes) ----------------
// fc1_wT  @ 4096     : [800][256] f32 (zero-padded k>=784)   819200 B
// fc2_wT  @ 823296   : [256][128] f32                        131072 B
// h3T     @ 954368   : [800][4096] f32 (rows>=784 unused)  13107200 B
// h1T     @ 14061568 : [256][4096] f32                      4194304 B
//   NOTE: conv tables live at OFF_H1T during {prep, conv_stack}; fc1 then
//   overwrites the region with h1T. Lifetimes are disjoint (same stream).
// h2T     @ 18255872 : [128][4096] f32                      2097152 B
#define OFF_W1T   4096
#define OFF_W2T   823296
#define OFF_H3T   954368
#define OFF_H1T   14061568
#define OFF_H2T   18255872

// table word offsets (int32 words, base = ws + OFF_H1T)
#define TW_WB1    0      // [32]  conv1 weight bits (9 taps in bits 0..8)
#define TW_W2     32     // [576] conv2 bits: [oc64][tap9], 32 ic bits
#define TW_W3     608    // [288] conv3 bits: [oc16][tap9][word2], 32 ic bits
#define TW_CORR2  896    // [16][64] border correction, conv2
#define TW_CORR3  1920   // [16][16] border correction, conv3
#define TW_TLE1   2176   // [32] conv1 interior: bit <=> Smin <= tle1
#define TW_TGE1   2208   // [32] conv1 border:   bit <=> Dmax >= tge1
#define TW_TLE2   2240   // [64] conv2 interior
#define TW_TGE2   2304   // [64] conv2 border
// total 2368 words = 9472 B  (h1T region is 4 MiB)

__device__ __forceinline__ int imin2(int a, int b) { return a < b ? a : b; }
__device__ __forceinline__ int imax2(int a, int b) { return a > b ? a : b; }

// ---------------- prep: pack bits, thresholds, corrections, FC transposes ---
__global__ __launch_bounds__(256) void prep(
    const float* __restrict__ w1, const float* __restrict__ b1,
    const float* __restrict__ w2, const float* __restrict__ b2,
    const float* __restrict__ w3,
    const float* __restrict__ fc1_w, const float* __restrict__ fc2_w,
    int* __restrict__ tab, float* __restrict__ w1T, float* __restrict__ w2T) {
    int t = threadIdx.x;
    uint32_t* utab = (uint32_t*)tab;
    if (blockIdx.x == 0) {
        if (t < 32) {
            uint32_t b = 0;
            for (int k = 0; k < 9; ++k) b |= (w1[t * 9 + k] > 0.f ? 1u : 0u) << k;
            utab[TW_WB1 + t] = b;
            tab[TW_TLE1 + t] = (int)floorf((9.f + b1[t]) * 0.5f);
            tab[TW_TGE1 + t] = (int)floorf(-b1[t]) + 1;
        }
        if (t >= 32 && t < 96) {
            int oc = t - 32;
            tab[TW_TLE2 + oc] = (int)floorf((288.f + b2[oc]) * 0.5f);
            tab[TW_TGE2 + oc] = (int)floorf(-b2[oc]) + 1;
        }
        for (int idx = t; idx < 576; idx += 256) {
            int oc = idx / 9, tap = idx % 9;
            int kh = tap / 3, kw = tap % 3;
            uint32_t b = 0;
            for (int ic = 0; ic < 32; ++ic)
                b |= (w2[((oc * 32 + ic) * 3 + kh) * 3 + kw] > 0.f ? 1u : 0u) << ic;
            utab[TW_W2 + idx] = b;
        }
        for (int idx = t; idx < 288; idx += 256) {
            int oc = idx / 18, rem = idx % 18;
            int tap = rem >> 1, word = rem & 1;
            int kh = tap / 3, kw = tap % 3;
            uint32_t b = 0;
            for (int ic = 0; ic < 32; ++ic)
                b |= (w3[((oc * 64 + ic + 32 * word) * 3 + kh) * 3 + kw] > 0.f ? 1u : 0u) << ic;
            utab[TW_W3 + idx] = b;
        }
        __syncthreads();   // packed words -> visible for correction pass
        for (int idx = t; idx < 1024; idx += 256) {
            int pat = idx >> 6, oc = idx & 63;
            int s = 0, n = 0;
            for (int tap = 0; tap < 9; ++tap) {
                int kh = tap / 3, kw = tap % 3;
                bool pad = ((pat & 1) && kh == 0) || ((pat & 2) && kh == 2) ||
                           ((pat & 4) && kw == 0) || ((pat & 8) && kw == 2);
                if (pad) { s += __popc(utab[TW_W2 + oc * 9 + tap]); ++n; }
            }
            tab[TW_CORR2 + idx] = 2 * s - 32 * n;
        }
        {
            int idx = t;
            if (idx < 256) {
                int pat = idx >> 4, oc = idx & 15;
                int s = 0, n = 0;
                for (int tap = 0; tap < 9; ++tap) {
                    int kh = tap / 3, kw = tap % 3;
                    bool pad = ((pat & 1) && kh == 0) || ((pat & 2) && kh == 2) ||
                               ((pat & 4) && kw == 0) || ((pat & 8) && kw == 2);
                    if (pad) {
                        s += __popc(utab[TW_W3 + oc * 18 + tap * 2]) +
                             __popc(utab[TW_W3 + oc * 18 + tap * 2 + 1]);
                        ++n;
                    }
                }
                tab[TW_CORR3 + idx] = 2 * s - 64 * n;
            }
        }
    } else {
        int e = (blockIdx.x - 1) * 256 + t;
        if (e < 204800) {                 // fc1_wT [800][256]
            int k = e >> 8, n = e & 255;
            w1T[e] = (k < 784) ? fc1_w[n * 784 + k] : 0.f;
        } else {                          // fc2_wT [256][128]
            int e2 = e - 204800;          // < 32768
            int k = e2 >> 7, n = e2 & 127;
            w2T[e2] = fc2_w[n * 256 + k];
        }
    }
}

// ---------------- conv stack: wave-per-image, lane = output channel ---------
// Per-wave LDS slice (words): [0..29] xrow (pre-shifted, zero pad rows 0/29)
//                             [32..287] H1 padded 16x16, [288..449] H2 9x9x2
#define WV_SIZE 456

__global__ __launch_bounds__(256, 6) void conv_stack(
    const float* __restrict__ x,
    const float* __restrict__ b3,
    const int* __restrict__ tab,
    float* __restrict__ h3T) {            // [800][4096]
    __shared__ uint32_t SH[4 * WV_SIZE];
    const int t = threadIdx.x;
    const int wid = t >> 6, lane = t & 63;
    const int img = blockIdx.x * 4 + wid;
    uint32_t* W = SH + wid * WV_SIZE;
    const uint32_t* utab = (const uint32_t*)tab;

    // zero wave-private region (H1/H2 borders must stay 0)
#pragma unroll
    for (int k = 0; k < 8; ++k) {
        int idx = lane + k * 64;
        if (idx < WV_SIZE) W[idx] = 0;
    }

    // load + binarize input rows: bit j+1 = (pixel j > 0), bits 0/29 = pad
    if (lane < 28) {
        const float* xr = x + img * 784 + lane * 28;
        uint32_t b = 0;
#pragma unroll
        for (int q = 0; q < 7; ++q) {
            float4 v = *(const float4*)(xr + q * 4);
            b |= (v.x > 0.f ? 1u : 0u) << (q * 4 + 0);
            b |= (v.y > 0.f ? 1u : 0u) << (q * 4 + 1);
            b |= (v.z > 0.f ? 1u : 0u) << (q * 4 + 2);
            b |= (v.w > 0.f ? 1u : 0u) << (q * 4 + 3);
        }
        W[1 + lane] = b << 1;
    }
    __syncthreads();

    // ---- conv1 (1->32) + pool + binarize -> H1 ----
    // interior pooled positions Pi,Pj in 1..12 (all taps valid): lane-parallel
    for (int it = 0; it < 3; ++it) {
        int p = it * 64 + lane;
        bool act = p < 144;
        int pp = act ? p : 0;
        int Pi = 1 + pp / 12, Pj = 1 + pp % 12;
        int i0 = 2 * Pi, j0 = 2 * Pj;
        uint32_t r0 = W[i0], r1 = W[i0 + 1], r2 = W[i0 + 2], r3 = W[i0 + 3];
        uint32_t f0a = (r0 >> j0) & 7, f0b = (r0 >> (j0 + 1)) & 7;
        uint32_t f1a = (r1 >> j0) & 7, f1b = (r1 >> (j0 + 1)) & 7;
        uint32_t f2a = (r2 >> j0) & 7, f2b = (r2 >> (j0 + 1)) & 7;
        uint32_t f3a = (r3 >> j0) & 7, f3b = (r3 >> (j0 + 1)) & 7;
        uint32_t s00 = f0a | (f1a << 3) | (f2a << 6);
        uint32_t s01 = f0b | (f1b << 3) | (f2b << 6);
        uint32_t s10 = f1a | (f2a << 3) | (f3a << 6);
        uint32_t s11 = f1b | (f2b << 3) | (f3b << 6);
        uint32_t word = 0;
#pragma unroll
        for (int oc = 0; oc < 32; ++oc) {
            uint32_t w = utab[TW_WB1 + oc];
            int m0 = __popc(s00 ^ w), m1 = __popc(s01 ^ w);
            int m2 = __popc(s10 ^ w), m3 = __popc(s11 ^ w);
            int mn = imin2(imin2(m0, m1), imin2(m2, m3));
            word |= (mn <= tab[TW_TLE1 + oc] ? 1u : 0u) << oc;
        }
        if (act) W[32 + (Pi + 1) * 16 + (Pj + 1)] = word;
    }
    // border pooled positions (52): masked taps
    {
        int p = lane;
        bool act = p < 52;
        int pp = act ? p : 28;
        int Pi, Pj;
        if (pp < 14)      { Pi = 0;  Pj = pp; }
        else if (pp < 28) { Pi = 13; Pj = pp - 14; }
        else if (pp < 40) { Pi = pp - 28 + 1; Pj = 0; }
        else              { Pi = pp - 40 + 1; Pj = 13; }
        int i0 = 2 * Pi, j0 = 2 * Pj;
        uint32_t r0 = W[i0], r1 = W[i0 + 1], r2 = W[i0 + 2], r3 = W[i0 + 3];
        uint32_t f0a = (r0 >> j0) & 7, f0b = (r0 >> (j0 + 1)) & 7;
        uint32_t f1a = (r1 >> j0) & 7, f1b = (r1 >> (j0 + 1)) & 7;
        uint32_t f2a = (r2 >> j0) & 7, f2b = (r2 >> (j0 + 1)) & 7;
        uint32_t f3a = (r3 >> j0) & 7, f3b = (r3 >> (j0 + 1)) & 7;
        uint32_t smp[4];
        smp[0] = f0a | (f1a << 3) | (f2a << 6);
        smp[1] = f0b | (f1b << 3) | (f2b << 6);
        smp[2] = f1a | (f2a << 3) | (f3a << 6);
        smp[3] = f1b | (f2b << 3) | (f3b << 6);
        uint32_t mb[4];
        int pcm[4];
#pragma unroll
        for (int a = 0; a < 2; ++a) {
            int i = 2 * Pi + a;
            uint32_t vre = 0x1FF;
            if (i == 0)  vre &= ~0x007u;
            if (i == 27) vre &= ~0x1C0u;
#pragma unroll
            for (int bb = 0; bb < 2; ++bb) {
                int j = 2 * Pj + bb;
                uint32_t vce = 0x1FF;
                if (j == 0)  vce &= ~0x049u;
                if (j == 27) vce &= ~0x124u;
                mb[a * 2 + bb] = vre & vce;
                pcm[a * 2 + bb] = __popc(vre & vce);
            }
        }
        uint32_t word = 0;
#pragma unroll
        for (int oc = 0; oc < 32; ++oc) {
            uint32_t w = utab[TW_WB1 + oc];
            int best = -1000;
#pragma unroll
            for (int p4 = 0; p4 < 4; ++p4) {
                int v = pcm[p4] - 2 * __popc((smp[p4] ^ w) & mb[p4]);
                best = imax2(best, v);
            }
            word |= (best >= tab[TW_TGE1 + oc] ? 1u : 0u) << oc;
        }
        if (act) W[32 + (Pi + 1) * 16 + (Pj + 1)] = word;
    }
    __syncthreads();

    // ---- conv2 (32->64) + pool + binarize -> H2 via ballot ----
    {
        uint32_t w2r[9];
#pragma unroll
        for (int k = 0; k < 9; ++k) w2r[k] = utab[TW_W2 + lane * 9 + k];
        const int tle2 = tab[TW_TLE2 + lane];
        const int tge2 = tab[TW_TGE2 + lane];
        const uint32_t* H1 = W + 32;
        uint32_t* H2 = W + 288;

        // interior pooled Pi,Pj in 1..5: no pad taps
        for (int Pi = 1; Pi <= 5; ++Pi) {
            for (int Pj = 1; Pj <= 5; ++Pj) {
                uint32_t c[16];
#pragma unroll
                for (int r = 0; r < 4; ++r) {
                    uint2 lo = *(const uint2*)&H1[(2 * Pi + r) * 16 + 2 * Pj];
                    uint2 hi = *(const uint2*)&H1[(2 * Pi + r) * 16 + 2 * Pj + 2];
                    c[r * 4 + 0] = lo.x; c[r * 4 + 1] = lo.y;
                    c[r * 4 + 2] = hi.x; c[r * 4 + 3] = hi.y;
                }
                int Sv[4];
#pragma unroll
                for (int a = 0; a < 2; ++a)
#pragma unroll
                    for (int bb = 0; bb < 2; ++bb) {
                        int s = 0;
#pragma unroll
                        for (int kh = 0; kh < 3; ++kh)
#pragma unroll
                            for (int kw = 0; kw < 3; ++kw)
                                s += __popc(c[(a + kh) * 4 + (bb + kw)] ^ w2r[kh * 3 + kw]);
                        Sv[a * 2 + bb] = s;
                    }
                int mn = imin2(imin2(Sv[0], Sv[1]), imin2(Sv[2], Sv[3]));
                uint64_t bal = __ballot(mn <= tle2);
                if (lane == 0) {
                    uint2 wv = make_uint2((uint32_t)bal, (uint32_t)(bal >> 32));
                    *(uint2*)&H2[((Pi + 1) * 9 + (Pj + 1)) * 2] = wv;
                }
            }
        }
        // border pooled (24): uniform popcount + pattern correction
        for (int bp = 0; bp < 24; ++bp) {
            int Pi, Pj;
            if (bp < 7)       { Pi = 0; Pj = bp; }
            else if (bp < 14) { Pi = 6; Pj = bp - 7; }
            else if (bp < 19) { Pi = bp - 14 + 1; Pj = 0; }
            else              { Pi = bp - 19 + 1; Pj = 6; }
            uint32_t c[16];
#pragma unroll
            for (int r = 0; r < 4; ++r) {
                uint2 lo = *(const uint2*)&H1[(2 * Pi + r) * 16 + 2 * Pj];
                uint2 hi = *(const uint2*)&H1[(2 * Pi + r) * 16 + 2 * Pj + 2];
                c[r * 4 + 0] = lo.x; c[r * 4 + 1] = lo.y;
                c[r * 4 + 2] = hi.x; c[r * 4 + 3] = hi.y;
            }
            int Sv[4];
#pragma unroll
            for (int a = 0; a < 2; ++a)
#pragma unroll
                for (int bb = 0; bb < 2; ++bb) {
                    int s = 0;
#pragma unroll
                    for (int kh = 0; kh < 3; ++kh)
#pragma unroll
                        for (int kw = 0; kw < 3; ++kw)
                            s += __popc(c[(a + kh) * 4 + (bb + kw)] ^ w2r[kh * 3 + kw]);
                    Sv[a * 2 + bb] = s;
                }
            int best = -100000;
#pragma unroll
            for (int a = 0; a < 2; ++a)
#pragma unroll
                for (int bb = 0; bb < 2; ++bb) {
                    int i = 2 * Pi + a, j = 2 * Pj + bb;
                    int pat = (i == 0 ? 1 : 0) | (i == 13 ? 2 : 0) |
                              (j == 0 ? 4 : 0) | (j == 13 ? 8 : 0);
                    int D = 288 - 2 * Sv[a * 2 + bb] + tab[TW_CORR2 + pat * 64 + lane];
                    best = imax2(best, D);
                }
            uint64_t bal = __ballot(best >= tge2);
            if (lane == 0) {
                uint2 wv = make_uint2((uint32_t)bal, (uint32_t)(bal >> 32));
                *(uint2*)&H2[((Pi + 1) * 9 + (Pj + 1)) * 2] = wv;
            }
        }
    }
    __syncthreads();

    // ---- conv3 (64->16) + bias + relu -> h3T[k][img] ----
    {
        const uint32_t* H2 = W + 288;
        int oc = lane & 15, sub = lane >> 4;
        uint32_t w3r[18];
#pragma unroll
        for (int k = 0; k < 18; ++k) w3r[k] = utab[TW_W3 + oc * 18 + k];
        float bias3 = b3[oc];
        for (int g = 0; g < 13; ++g) {
            int pos = g * 4 + sub;
            bool act = pos < 49;
            int pp = act ? pos : 0;
            int Pi = pp / 7, Pj = pp % 7;
            int s = 0;
#pragma unroll
            for (int kh = 0; kh < 3; ++kh)
#pragma unroll
                for (int kw = 0; kw < 3; ++kw) {
                    uint2 hv = *(const uint2*)&H2[((Pi + kh) * 9 + (Pj + kw)) * 2];
                    s += __popc(hv.x ^ w3r[(kh * 3 + kw) * 2]) +
                         __popc(hv.y ^ w3r[(kh * 3 + kw) * 2 + 1]);
                }
            int pat = (Pi == 0 ? 1 : 0) | (Pi == 6 ? 2 : 0) |
                      (Pj == 0 ? 4 : 0) | (Pj == 6 ? 8 : 0);
            int D = 576 - 2 * s + tab[TW_CORR3 + pat * 16 + oc];
            float h = (float)D + bias3;
            h = h > 0.f ? h : 0.f;
            if (act) h3T[(oc * 49 + pp) * 4096 + img] = h;
        }
    }
}

// ---------------- FC1: [4096x800] x [800x256] -> relu -> h1T ----------------
__global__ __launch_bounds__(256) void fc1_gemm(
    const float* __restrict__ aT,    // h3T [800][4096]
    const float* __restrict__ bT,    // fc1_wT [800][256]
    const float* __restrict__ bias,
    float* __restrict__ oT) {        // h1T [256][4096]
    const int KC = 80, LD = 68;
    __shared__ float As[KC * LD];
    __shared__ float Bs[KC * LD];
    const int t = threadIdx.x;
    const int tx = t & 15, ty = t >> 4;
    const int img0 = blockIdx.x * 64;
    const int n0 = blockIdx.y * 64;
    float acc[4][4] = {{0.f}};

    for (int kc = 0; kc < 800; kc += KC) {
#pragma unroll
        for (int s = 0; s < 5; ++s) {
            int v = t + s * 256;
            int kk = v >> 4, i4 = (v & 15) * 4;
            *(float4*)&As[kk * LD + i4] =
                *(const float4*)&aT[(kc + kk) * 4096 + img0 + i4];
            *(float4*)&Bs[kk * LD + i4] =
                *(const float4*)&bT[(kc + kk) * 256 + n0 + i4];
        }
        __syncthreads();
#pragma unroll 4
        for (int kk = 0; kk < KC; ++kk) {
            float4 a = *(const float4*)&As[kk * LD + ty * 4];
            float4 b = *(const float4*)&Bs[kk * LD + tx * 4];
            acc[0][0] += a.x * b.x; acc[0][1] += a.x * b.y;
            acc[0][2] += a.x * b.z; acc[0][3] += a.x * b.w;
            acc[1][0] += a.y * b.x; acc[1][1] += a.y * b.y;
            acc[1][2] += a.y * b.z; acc[1][3] += a.y * b.w;
            acc[2][0] += a.z * b.x; acc[2][1] += a.z * b.y;
            acc[2][2] += a.z * b.z; acc[2][3] += a.z * b.w;
            acc[3][0] += a.w * b.x; acc[3][1] += a.w * b.y;
            acc[3][2] += a.w * b.z; acc[3][3] += a.w * b.w;
        }
        __syncthreads();
    }
    float4 bb = *(const float4*)&bias[n0 + tx * 4];
    float bv[4] = {bb.x, bb.y, bb.z, bb.w};
#pragma unroll
    for (int jj = 0; jj < 4; ++jj) {
        float4 ov;
        ov.x = acc[0][jj] + bv[jj]; ov.x = ov.x > 0.f ? ov.x : 0.f;
        ov.y = acc[1][jj] + bv[jj]; ov.y = ov.y > 0.f ? ov.y : 0.f;
        ov.z = acc[2][jj] + bv[jj]; ov.z = ov.z > 0.f ? ov.z : 0.f;
        ov.w = acc[3][jj] + bv[jj]; ov.w = ov.w > 0.f ? ov.w : 0.f;
        *(float4*)&oT[(n0 + tx * 4 + jj) * 4096 + img0 + ty * 4] = ov;
    }
}

// ---------------- FC2: [4096x256] x [256x128] -> relu -> h2T ----------------
__global__ __launch_bounds__(256) void fc2_gemm(
    const float* __restrict__ aT,    // h1T [256][4096]
    const float* __restrict__ bT,    // fc2_wT [256][128]
    const float* __restrict__ bias,
    float* __restrict__ oT) {        // h2T [128][4096]
    const int KC = 64, LDA = 68, LDB = 36;
    __shared__ float As[KC * LDA];
    __shared__ float Bs[KC * LDB];
    const int t = threadIdx.x;
    const int tx = t & 15, ty = t >> 4;
    const int img0 = blockIdx.x * 64;
    const int n0 = blockIdx.y * 32;
    float acc[4][2] = {{0.f}};

    for (int kc = 0; kc < 256; kc += KC) {
#pragma unroll
        for (int s = 0; s < 4; ++s) {
            int v = t + s * 256;
            int kk = v >> 4, i4 = (v & 15) * 4;
            *(float4*)&As[kk * LDA + i4] =
                *(const float4*)&aT[(kc + kk) * 4096 + img0 + i4];
        }
#pragma unroll
        for (int s = 0; s < 2; ++s) {
            int v = t + s * 256;
            int kk = v >> 3, n4 = (v & 7) * 4;
            *(float4*)&Bs[kk * LDB + n4] =
                *(const float4*)&bT[(kc + kk) * 128 + n0 + n4];
        }
        __syncthreads();
#pragma unroll 4
        for (int kk = 0; kk < KC; ++kk) {
            float4 a = *(const float4*)&As[kk * LDA + ty * 4];
            float2 b = *(const float2*)&Bs[kk * LDB + tx * 2];
            acc[0][0] += a.x * b.x; acc[0][1] += a.x * b.y;
            acc[1][0] += a.y * b.x; acc[1][1] += a.y * b.y;
            acc[2][0] += a.z * b.x; acc[2][1] += a.z * b.y;
            acc[3][0] += a.w * b.x; acc[3][1] += a.w * b.y;
        }
        __syncthreads();
    }
#pragma unroll
    for (int j = 0; j < 2; ++j) {
        int n = n0 + tx * 2 + j;
        float bj = bias[n];
        float4 ov;
        ov.x = acc[0][j] + bj; ov.x = ov.x > 0.f ? ov.x : 0.f;
        ov.y = acc[1][j] + bj; ov.y = ov.y > 0.f ? ov.y : 0.f;
        ov.z = acc[2][j] + bj; ov.z = ov.z > 0.f ? ov.z : 0.f;
        ov.w = acc[3][j] + bj; ov.w = ov.w > 0.f ? ov.w : 0.f;
        *(float4*)&oT[n * 4096 + img0 + ty * 4] = ov;
    }
}

// ---------------- FC3: [4096x128] x [128x10] -> out -------------------------
__global__ __launch_bounds__(256) void fc3_gemm(
    const float* __restrict__ aT,    // h2T [128][4096]
    const float* __restrict__ w,     // fc3_w [10][128]
    const float* __restrict__ bias,
    float* __restrict__ out) {       // [4096][10]
    int id = blockIdx.x * 256 + threadIdx.x;   // 40960
    int n = id >> 12, img = id & 4095;
    const float* wr = w + n * 128;
    float a0 = 0.f, a1 = 0.f, a2 = 0.f, a3 = 0.f;
#pragma unroll 8
    for (int k = 0; k < 128; k += 4) {
        a0 += aT[(k + 0) * 4096 + img] * wr[k + 0];
        a1 += aT[(k + 1) * 4096 + img] * wr[k + 1];
        a2 += aT[(k + 2) * 4096 + img] * wr[k + 2];
        a3 += aT[(k + 3) * 4096 + img] * wr[k + 3];
    }
    out[img * 10 + n] = (a0 + a1) + (a2 + a3) + bias[n];
}

extern "C" void kernel_launch(void* const* d_in, const int* in_sizes, int n_in,
                              void* d_out, int out_size, void* d_ws, size_t ws_size,
                              hipStream_t stream) {
    const float* x     = (const float*)d_in[0];
    const float* w1    = (const float*)d_in[1];
    const float* b1    = (const float*)d_in[2];
    const float* w2    = (const float*)d_in[3];
    const float* b2    = (const float*)d_in[4];
    const float* w3    = (const float*)d_in[5];
    const float* b3    = (const float*)d_in[6];
    const float* fc1_w = (const float*)d_in[7];
    const float* fc1_b = (const float*)d_in[8];
    const float* fc2_w = (const float*)d_in[9];
    const float* fc2_b = (const float*)d_in[10];
    const float* fc3_w = (const float*)d_in[11];
    const float* fc3_b = (const float*)d_in[12];
    float* out = (float*)d_out;

    const int B = in_sizes[0] / 784;  // 4096
    char* ws = (char*)d_ws;
    float* w1T = (float*)(ws + OFF_W1T);
    float* w2T = (float*)(ws + OFF_W2T);
    float* h3T = (float*)(ws + OFF_H3T);
    float* h1T = (float*)(ws + OFF_H1T);
    float* h2T = (float*)(ws + OFF_H2T);
    int* tab = (int*)(ws + OFF_H1T);  // tables alias h1T (disjoint lifetime)

    hipLaunchKernelGGL(prep, dim3(929), dim3(256), 0, stream,
                       w1, b1, w2, b2, w3, fc1_w, fc2_w, tab, w1T, w2T);
    hipLaunchKernelGGL(conv_stack, dim3(B / 4), dim3(256), 0, stream,
                       x, b3, tab, h3T);
    hipLaunchKernelGGL(fc1_gemm, dim3(B / 64, 4), dim3(256), 0, stream,
                       h3T, w1T, fc1_b, h1T);
    hipLaunchKernelGGL(fc2_gemm, dim3(B / 64, 4), dim3(256), 0, stream,
                       h1T, w2T, fc2_b, h2T);
    hipLaunchKernelGGL(fc3_gemm, dim3(B * 10 / 256), dim3(256), 0, stream,
                       h2T, fc3_w, fc3_b, out);
}